// Round 1
// baseline (7016.064 us; speedup 1.0000x reference)
//
#include <hip/hip_runtime.h>

#define BB 64
#define TT 512
#define EE 128
#define HH 512
#define NGRP 4
#define BG 16
#define NSLICE 32
#define JW 16
#define DOMBLK 32
#define NSLOT 132
#define LDH 520   // 512 + 8 fp16 pad (row stride 1040B -> 2-way-free LDS banks)
#define LDE 136   // 128 + 8

typedef _Float16 f16;
typedef f16 f16x8 __attribute__((ext_vector_type(8)));
typedef float floatx4 __attribute__((ext_vector_type(4)));

__device__ __forceinline__ float sigmf(float x) { return 1.f / (1.f + __expf(-x)); }
__device__ __forceinline__ float tanhfast(float x) { return 2.f / (1.f + __expf(-2.f * x)) - 1.f; }

// ---------------- slot map: for each (b,t), compact slot index if t is referenced by boundary ----------------
__global__ __launch_bounds__(64) void build_map(const int* __restrict__ bnd,
                                                int* __restrict__ slotmap)
{
  __shared__ unsigned char need[TT];
  const int b = blockIdx.x;
  for (int i = threadIdx.x; i < TT; i += 64) need[i] = 0;
  __syncthreads();
  {
    const int w = threadIdx.x;              // 0..63
    const int iv = bnd[b * 65 + w];
    const int jv = bnd[b * 65 + w + 1];
    if (iv != -1 && jv != -1) {
      int ic = iv < 0 ? 0 : (iv > TT - 1 ? TT - 1 : iv);
      int jc = jv < 0 ? 0 : (jv > TT - 1 ? TT - 1 : jv);
      need[ic] = 1;
      need[jc] = 1;
    }
  }
  __syncthreads();
  if (threadIdx.x == 0) {
    int c = 0;
    for (int t = 0; t < TT; ++t) slotmap[b * TT + t] = need[t] ? (c++) : -1;
  }
}

// ---------------- persistent bidirectional LSTM scan ----------------
// grid = 256 blocks x 256 threads. block -> (domain = blockIdx&7 = (dir,grp), slice = blockIdx>>3).
// domain = 32 blocks covering hidden dims; custom arrive/spin sync per domain per step.
__global__ __launch_bounds__(256, 1) void lstm_scan(
    const int* __restrict__ ids, const int* __restrict__ maskI,
    const float* __restrict__ emb,
    const float* __restrict__ Wih_f, const float* __restrict__ Whh_f, const float* __restrict__ b_f,
    const float* __restrict__ Wih_b, const float* __restrict__ Whh_b, const float* __restrict__ b_b,
    const int* __restrict__ slotmap,
    f16* __restrict__ h_g,        // [2 buf][2 dir][NGRP][BG][HH] fp16 ping-pong h exchange
    f16* __restrict__ hist,       // [2 dir][BB][NSLOT][HH] fp16 (h*mask at needed t)
    unsigned* __restrict__ cnt)   // [8 domains], stride 32 u32 (128B apart)
{
  __shared__ f16 sH[BG * LDH];
  __shared__ f16 sX[BG * LDE];
  __shared__ float sMask[BG];
  __shared__ int sSlot[BG];

  const int tid = threadIdx.x;
  const int bid = blockIdx.x;
  const int dom = bid & 7;
  const int slice = bid >> 3;          // 0..31
  const int dir = dom & 1;
  const int grp = dom >> 1;

  const float* Wih = dir ? Wih_b : Wih_f;
  const float* Whh = dir ? Whh_b : Whh_f;
  const float* bv  = dir ? b_b   : b_f;

  const int lane = tid & 63;
  const int wave = tid >> 6;           // 0..3 (one 16-col N-tile per wave)
  const int rloc = lane & 15;
  const int kg   = lane >> 4;          // 0..3 (k-group of the fragment)
  const int rglob = wave * 16 + rloc;  // gate-row within block slice, 0..63; ordered r = jloc*4 + type
  const int jloc  = rglob >> 2;        // 0..15 hidden dim within slice
  const int q     = rglob & 3;         // gate type of this lane's column (0=i,1=f,2=g,3=o)
  const int jglob = slice * JW + jloc; // global hidden dim 0..511
  const int mbase = kg * 4;            // batch base of this lane's 4 acc rows

  const int growL = q * HH + slice * JW + jloc;   // row of Whh/Wih/bias in [0,2048)

  // --- preload step-invariant B fragments (Whh, Wih) into registers, fp32 -> fp16 ---
  f16x8 wh[16];
  {
    const float* wr = Whh + (size_t)growL * HH + kg * 8;
    #pragma unroll
    for (int kk = 0; kk < 16; ++kk) {
      float4 a0 = *(const float4*)(wr + kk * 32);
      float4 a1 = *(const float4*)(wr + kk * 32 + 4);
      f16x8 v;
      v[0]=(f16)a0.x; v[1]=(f16)a0.y; v[2]=(f16)a0.z; v[3]=(f16)a0.w;
      v[4]=(f16)a1.x; v[5]=(f16)a1.y; v[6]=(f16)a1.z; v[7]=(f16)a1.w;
      wh[kk] = v;
    }
  }
  f16x8 wx[4];
  {
    const float* wr = Wih + (size_t)growL * EE + kg * 8;
    #pragma unroll
    for (int kk = 0; kk < 4; ++kk) {
      float4 a0 = *(const float4*)(wr + kk * 32);
      float4 a1 = *(const float4*)(wr + kk * 32 + 4);
      f16x8 v;
      v[0]=(f16)a0.x; v[1]=(f16)a0.y; v[2]=(f16)a0.z; v[3]=(f16)a0.w;
      v[4]=(f16)a1.x; v[5]=(f16)a1.y; v[6]=(f16)a1.z; v[7]=(f16)a1.w;
      wx[kk] = v;
    }
  }
  const float bsc = bv[growL];

  float cc[4] = {0.f, 0.f, 0.f, 0.f};   // c state: 4 batches (mbase..mbase+3) x this quad's jloc
  float hh[4] = {0.f, 0.f, 0.f, 0.f};   // h state (fp16-rounded, kept in f32)

  for (int s = 0; s < TT; ++s) {
    const int t = dir ? (TT - 1 - s) : s;

    // ---- stage h_s (or zeros at s==0) into LDS ----
    if (s == 0) {
      for (int e = tid; e < BG * 64; e += 256) {
        const int row = e >> 6, ch = e & 63;
        uint4 z = make_uint4(0u, 0u, 0u, 0u);
        *(uint4*)(sH + row * LDH + ch * 8) = z;
      }
    } else {
      const f16* hsrc = h_g + ((size_t)(((s & 1) * 2 + dir) * NGRP + grp)) * BG * HH;
      #pragma unroll
      for (int i = 0; i < 4; ++i) {
        const int e = tid * 4 + i;          // 0..1023 chunks of 8 fp16
        const int row = e >> 6, ch = e & 63;
        uint4 v = *(const uint4*)(hsrc + row * HH + ch * 8);
        *(uint4*)(sH + row * LDH + ch * 8) = v;
      }
    }
    // ---- stage x_t = emb[ids[b,t]] fp32 -> fp16 LDS ----
    {
      const int row = tid >> 4;             // 0..15 batch row
      const int c0 = (tid & 15) * 8;        // 0..120
      const int b = grp * BG + row;
      const int idx = ids[b * TT + t];
      float4 x0 = *(const float4*)(emb + (size_t)idx * EE + c0);
      float4 x1 = *(const float4*)(emb + (size_t)idx * EE + c0 + 4);
      f16x8 xv;
      xv[0]=(f16)x0.x; xv[1]=(f16)x0.y; xv[2]=(f16)x0.z; xv[3]=(f16)x0.w;
      xv[4]=(f16)x1.x; xv[5]=(f16)x1.y; xv[6]=(f16)x1.z; xv[7]=(f16)x1.w;
      *(f16x8*)(sX + row * LDE + c0) = xv;
    }
    if (tid < BG) {
      const int b = grp * BG + tid;
      sMask[tid] = (float)maskI[b * TT + t];
      sSlot[tid] = slotmap[b * TT + t];
    }
    __syncthreads();

    // ---- gates[16 batch, 16 gate-rows] = h @ Whh_slice^T + x @ Wih_slice^T ----
    floatx4 acc = {0.f, 0.f, 0.f, 0.f};
    const f16* aH = sH + rloc * LDH + kg * 8;
    #pragma unroll
    for (int kk = 0; kk < 16; ++kk) {
      f16x8 af = *(const f16x8*)(aH + kk * 32);
      acc = __builtin_amdgcn_mfma_f32_16x16x32_f16(af, wh[kk], acc, 0, 0, 0);
    }
    const f16* aX = sX + rloc * LDE + kg * 8;
    #pragma unroll
    for (int kk = 0; kk < 4; ++kk) {
      f16x8 af = *(const f16x8*)(aX + kk * 32);
      acc = __builtin_amdgcn_mfma_f32_16x16x32_f16(af, wx[kk], acc, 0, 0, 0);
    }

    // ---- epilogue: quad-exchange the 4 gate types, LSTM cell update ----
    float hstore[4];
    #pragma unroll
    for (int i = 0; i < 4; ++i) {
      const float g0 = acc[i] + bsc;
      const float s1 = __shfl_xor(g0, 1, 64);
      const float s2 = __shfl_xor(g0, 2, 64);
      const float s3 = __shfl_xor(s1, 2, 64);
      float vi, vf, vg, vo;
      if (q == 0)      { vi = g0; vf = s1; vg = s2; vo = s3; }
      else if (q == 1) { vi = s1; vf = g0; vg = s3; vo = s2; }
      else if (q == 2) { vi = s2; vf = s3; vg = g0; vo = s1; }
      else             { vi = s3; vf = s2; vg = s1; vo = g0; }
      const float ig = sigmf(vi);
      const float fg = sigmf(vf);
      const float gt = tanhfast(vg);
      const float og = sigmf(vo);
      const float cn = fg * cc[i] + ig * gt;
      const float hn = og * tanhfast(cn);
      const float m = sMask[mbase + i];
      cc[i] = m > 0.f ? cn : cc[i];
      float hk = m > 0.f ? hn : hh[i];
      const f16 h16 = (f16)hk;                 // round state to fp16 so all consumers agree
      hh[i] = (float)h16;
      hstore[i] = m > 0.f ? (float)h16 : 0.f;  // ys = h * m
    }
    // ---- each lane stores its (batch mbase+q, jglob) element ----
    {
      const float hq = (q == 0) ? hh[0] : (q == 1) ? hh[1] : (q == 2) ? hh[2] : hh[3];
      const float hs = (q == 0) ? hstore[0] : (q == 1) ? hstore[1] : (q == 2) ? hstore[2] : hstore[3];
      const int bl = mbase + q;
      f16* hdst = h_g + ((size_t)((((s + 1) & 1) * 2 + dir) * NGRP + grp) * BG + bl) * HH + jglob;
      *hdst = (f16)hq;
      const int slot = sSlot[bl];
      if (slot >= 0) {
        const int bgl = grp * BG + bl;
        hist[((size_t)(dir * BB + bgl) * NSLOT + slot) * HH + jglob] = (f16)hs;
      }
    }
    __syncthreads();                        // all stores drained (waitcnt before barrier)
    if (s + 1 < TT) {
      if (tid == 0) {
        __hip_atomic_fetch_add(&cnt[dom * 32], 1u, __ATOMIC_RELEASE, __HIP_MEMORY_SCOPE_AGENT);
        const unsigned tgt = (unsigned)(s + 1) * DOMBLK;
        while (__hip_atomic_load(&cnt[dom * 32], __ATOMIC_RELAXED, __HIP_MEMORY_SCOPE_AGENT) < tgt) {
          __builtin_amdgcn_s_sleep(2);
        }
        __threadfence();                    // acquire: invalidate stale lines before h_g reads
      }
      __syncthreads();
    }
  }
}

// ---------------- gather boundary outputs ----------------
__global__ __launch_bounds__(256) void gather_out(
    const int* __restrict__ bnd, const int* __restrict__ slotmap,
    const f16* __restrict__ hist, float* __restrict__ out)
{
  const int bw = blockIdx.x;       // b*64 + w
  const int b = bw >> 6;
  const int w = bw & 63;
  const int k = threadIdx.x * 8;   // 0..2047
  const int iv = bnd[b * 65 + w];
  const int jv = bnd[b * 65 + w + 1];
  const bool valid = (iv != -1) && (jv != -1);
  float* dst = out + (size_t)bw * 2048 + k;
  if (valid) {
    const int seg = k >> 9;                    // 0: h_f(i) 1: h_b(i) 2: h_f(j) 3: h_b(j)
    int ts = (seg < 2) ? iv : jv;
    ts = ts < 0 ? 0 : (ts > TT - 1 ? TT - 1 : ts);
    const int dirn = seg & 1;
    const int slot = slotmap[b * TT + ts];
    const f16* src = hist + ((size_t)(dirn * BB + b) * NSLOT + slot) * HH + (k & 511);
    f16x8 v = *(const f16x8*)src;
    float4 o0 = make_float4((float)v[0], (float)v[1], (float)v[2], (float)v[3]);
    float4 o1 = make_float4((float)v[4], (float)v[5], (float)v[6], (float)v[7]);
    *(float4*)dst = o0;
    *(float4*)(dst + 4) = o1;
  } else {
    float4 z = make_float4(0.f, 0.f, 0.f, 0.f);
    *(float4*)dst = z;
    *(float4*)(dst + 4) = z;
  }
}

extern "C" void kernel_launch(void* const* d_in, const int* in_sizes, int n_in,
                              void* d_out, int out_size, void* d_ws, size_t ws_size,
                              hipStream_t stream)
{
  (void)in_sizes; (void)n_in; (void)out_size; (void)ws_size;
  const int* ids     = (const int*)d_in[0];
  const int* maskI   = (const int*)d_in[1];
  const int* bnd     = (const int*)d_in[2];
  const float* emb   = (const float*)d_in[3];
  const float* Wih_f = (const float*)d_in[4];
  const float* Whh_f = (const float*)d_in[5];
  const float* b_f   = (const float*)d_in[6];
  const float* Wih_b = (const float*)d_in[7];
  const float* Whh_b = (const float*)d_in[8];
  const float* b_b   = (const float*)d_in[9];

  char* ws = (char*)d_ws;
  unsigned* cnt = (unsigned*)ws;                                   // 4 KiB (8 counters, 128B apart)
  int* slotmap  = (int*)(ws + 4096);                               // 64*512*4 = 128 KiB
  f16* h_g      = (f16*)(ws + 4096 + 131072);                      // 2*2*4*16*512*2 = 256 KiB
  f16* hist     = (f16*)(ws + 4096 + 131072 + 262144);             // 2*64*132*512*2 ~= 16.5 MiB

  hipMemsetAsync(cnt, 0, 4096, stream);
  build_map<<<dim3(BB), dim3(64), 0, stream>>>(bnd, slotmap);
  lstm_scan<<<dim3(256), dim3(256), 0, stream>>>(ids, maskI, emb,
      Wih_f, Whh_f, b_f, Wih_b, Whh_b, b_b, slotmap, h_g, hist, cnt);
  gather_out<<<dim3(BB * 64), dim3(256), 0, stream>>>(bnd, slotmap, hist, (float*)d_out);
}

// Round 3
// 1939.417 us; speedup vs baseline: 3.6176x; 3.6176x over previous
//
#include <hip/hip_runtime.h>

#define BB 64
#define TT 512
#define EE 128
#define HH 512
#define NGRP 4
#define BG 16
#define NSLICE 32
#define JW 16
#define DOMBLK 32
#define NSLOT 132
#define LDH 520   // 512 + 8 fp16 pad
#define LDE 136   // 128 + 8

typedef _Float16 f16;
typedef f16 f16x8 __attribute__((ext_vector_type(8)));
typedef float floatx4 __attribute__((ext_vector_type(4)));
typedef unsigned long long u64;

__device__ __forceinline__ float sigmf(float x) { return 1.f / (1.f + __expf(-x)); }
__device__ __forceinline__ float tanhfast(float x) { return 2.f / (1.f + __expf(-2.f * x)) - 1.f; }

// ---------------- slot map ----------------
__global__ __launch_bounds__(64) void build_map(const int* __restrict__ bnd,
                                                int* __restrict__ slotmap)
{
  __shared__ unsigned char need[TT];
  const int b = blockIdx.x;
  for (int i = threadIdx.x; i < TT; i += 64) need[i] = 0;
  __syncthreads();
  {
    const int w = threadIdx.x;
    const int iv = bnd[b * 65 + w];
    const int jv = bnd[b * 65 + w + 1];
    if (iv != -1 && jv != -1) {
      int ic = iv < 0 ? 0 : (iv > TT - 1 ? TT - 1 : iv);
      int jc = jv < 0 ? 0 : (jv > TT - 1 ? TT - 1 : jv);
      need[ic] = 1;
      need[jc] = 1;
    }
  }
  __syncthreads();
  if (threadIdx.x == 0) {
    int c = 0;
    for (int t = 0; t < TT; ++t) slotmap[b * TT + t] = need[t] ? (c++) : -1;
  }
}

// ---------------- persistent bidirectional LSTM scan ----------------
// 256 blocks x 256 threads; domain = blockIdx&7 = (dir,grp) of 32 slice-blocks.
// Per-step barrier: sc1 (agent-coherent, L3) data stores + vmcnt(0) + relaxed
// flag store; readers poll the 128B flag line. NO buffer_wbl2 / buffer_inv.
__global__ __launch_bounds__(256, 1) void lstm_scan(
    const int* __restrict__ ids, const int* __restrict__ maskI,
    const float* __restrict__ emb,
    const float* __restrict__ Wih_f, const float* __restrict__ Whh_f, const float* __restrict__ b_f,
    const float* __restrict__ Wih_b, const float* __restrict__ Whh_b, const float* __restrict__ b_b,
    const int* __restrict__ slotmap,
    f16* __restrict__ h_g,        // [2 buf][2 dir][NGRP][BG][HH] fp16 ping-pong
    f16* __restrict__ hist,       // [2 dir][BB][NSLOT][HH] fp16
    unsigned* __restrict__ flags) // [8 domains][32 slices] u32, one 128B line/domain
{
  __shared__ f16 sH[BG * LDH];
  __shared__ f16 sX[BG * LDE];
  __shared__ f16 hOut[BG * JW];   // [batch][jloc] this block's slice output
  __shared__ float sMask[BG];
  __shared__ int sSlot[BG];

  const int tid = threadIdx.x;
  const int bid = blockIdx.x;
  const int dom = bid & 7;
  const int slice = bid >> 3;          // 0..31
  const int dir = dom & 1;
  const int grp = dom >> 1;

  const float* Wih = dir ? Wih_b : Wih_f;
  const float* Whh = dir ? Whh_b : Whh_f;
  const float* bv  = dir ? b_b   : b_f;

  const int lane = tid & 63;
  const int wave = tid >> 6;
  const int rloc = lane & 15;
  const int kg   = lane >> 4;
  const int rglob = wave * 16 + rloc;  // gate-row in slice, r = jloc*4 + q
  const int jloc  = rglob >> 2;
  const int q     = rglob & 3;         // 0=i,1=f,2=g,3=o
  const int mbase = kg * 4;

  const int growL = q * HH + slice * JW + jloc;

  // --- preload step-invariant weights into registers (fp32 -> fp16) ---
  f16x8 wh[16];
  {
    const float* wr = Whh + (size_t)growL * HH + kg * 8;
    #pragma unroll
    for (int kk = 0; kk < 16; ++kk) {
      float4 a0 = *(const float4*)(wr + kk * 32);
      float4 a1 = *(const float4*)(wr + kk * 32 + 4);
      f16x8 v;
      v[0]=(f16)a0.x; v[1]=(f16)a0.y; v[2]=(f16)a0.z; v[3]=(f16)a0.w;
      v[4]=(f16)a1.x; v[5]=(f16)a1.y; v[6]=(f16)a1.z; v[7]=(f16)a1.w;
      wh[kk] = v;
    }
  }
  f16x8 wx[4];
  {
    const float* wr = Wih + (size_t)growL * EE + kg * 8;
    #pragma unroll
    for (int kk = 0; kk < 4; ++kk) {
      float4 a0 = *(const float4*)(wr + kk * 32);
      float4 a1 = *(const float4*)(wr + kk * 32 + 4);
      f16x8 v;
      v[0]=(f16)a0.x; v[1]=(f16)a0.y; v[2]=(f16)a0.z; v[3]=(f16)a0.w;
      v[4]=(f16)a1.x; v[5]=(f16)a1.y; v[6]=(f16)a1.z; v[7]=(f16)a1.w;
      wx[kk] = v;
    }
  }
  const float bsc = bv[growL];

  float cc[4] = {0.f, 0.f, 0.f, 0.f};
  float hh[4] = {0.f, 0.f, 0.f, 0.f};

  for (int s = 0; s < TT; ++s) {
    const int t = dir ? (TT - 1 - s) : s;

    // ---- stage x_t (plain L2 loads, issued first) ----
    {
      const int row = tid >> 4;
      const int c0 = (tid & 15) * 8;
      const int b = grp * BG + row;
      const int idx = ids[b * TT + t];
      float4 x0 = *(const float4*)(emb + (size_t)idx * EE + c0);
      float4 x1 = *(const float4*)(emb + (size_t)idx * EE + c0 + 4);
      f16x8 xv;
      xv[0]=(f16)x0.x; xv[1]=(f16)x0.y; xv[2]=(f16)x0.z; xv[3]=(f16)x0.w;
      xv[4]=(f16)x1.x; xv[5]=(f16)x1.y; xv[6]=(f16)x1.z; xv[7]=(f16)x1.w;
      *(f16x8*)(sX + row * LDE + c0) = xv;
    }
    if (tid < BG) {
      const int b = grp * BG + tid;
      sMask[tid] = (float)maskI[b * TT + t];
      sSlot[tid] = slotmap[b * TT + t];
    }

    // ---- stage h_s: agent-coherent (sc1) loads from L3, no cache inv ----
    if (s == 0) {
      for (int e = tid; e < BG * 64; e += 256) {
        const int row = e >> 6, ch = e & 63;
        uint4 z = make_uint4(0u, 0u, 0u, 0u);
        *(uint4*)(sH + row * LDH + ch * 8) = z;
      }
    } else {
      const u64* hq = (const u64*)(h_g + ((size_t)(((s & 1) * 2 + dir) * NGRP + grp)) * BG * HH);
      u64 v[8];
      #pragma unroll
      for (int p = 0; p < 8; ++p)
        v[p] = __hip_atomic_load(hq + p * 256 + tid, __ATOMIC_RELAXED, __HIP_MEMORY_SCOPE_AGENT);
      #pragma unroll
      for (int p = 0; p < 8; ++p) {
        const int e = p * 256 + tid;        // 8B chunk index; 128 chunks per 512-f16 row
        const int row = e >> 7, ch = e & 127;
        *(u64*)(sH + row * LDH + ch * 4) = v[p];
      }
    }
    __syncthreads();

    // ---- gates = h @ Whh^T + x @ Wih^T (MFMA, weights register-resident) ----
    floatx4 acc = {0.f, 0.f, 0.f, 0.f};
    const f16* aH = sH + rloc * LDH + kg * 8;
    #pragma unroll
    for (int kk = 0; kk < 16; ++kk) {
      f16x8 af = *(const f16x8*)(aH + kk * 32);
      acc = __builtin_amdgcn_mfma_f32_16x16x32_f16(af, wh[kk], acc, 0, 0, 0);
    }
    const f16* aX = sX + rloc * LDE + kg * 8;
    #pragma unroll
    for (int kk = 0; kk < 4; ++kk) {
      f16x8 af = *(const f16x8*)(aX + kk * 32);
      acc = __builtin_amdgcn_mfma_f32_16x16x32_f16(af, wx[kk], acc, 0, 0, 0);
    }

    // ---- epilogue: quad-exchange gate types, LSTM cell update ----
    #pragma unroll
    for (int i = 0; i < 4; ++i) {
      const float g0 = acc[i] + bsc;
      const float s1 = __shfl_xor(g0, 1, 64);
      const float s2 = __shfl_xor(g0, 2, 64);
      const float s3 = __shfl_xor(s1, 2, 64);
      float vi, vf, vg, vo;
      if (q == 0)      { vi = g0; vf = s1; vg = s2; vo = s3; }
      else if (q == 1) { vi = s1; vf = g0; vg = s3; vo = s2; }
      else if (q == 2) { vi = s2; vf = s3; vg = g0; vo = s1; }
      else             { vi = s3; vf = s2; vg = s1; vo = g0; }
      const float ig = sigmf(vi);
      const float fg = sigmf(vf);
      const float gt = tanhfast(vg);
      const float og = sigmf(vo);
      const float cn = fg * cc[i] + ig * gt;
      const float hn = og * tanhfast(cn);
      const float m = sMask[mbase + i];
      cc[i] = m > 0.f ? cn : cc[i];
      float hk = m > 0.f ? hn : hh[i];
      const f16 h16 = (f16)hk;            // round state to fp16 so all consumers agree
      hh[i] = (float)h16;
    }
    // each lane owns (batch mbase+q, jloc) -> LDS slice buffer
    {
      const float hq_ = (q == 0) ? hh[0] : (q == 1) ? hh[1] : (q == 2) ? hh[2] : hh[3];
      hOut[(mbase + q) * JW + jloc] = (f16)hq_;
    }
    __syncthreads();

    // ---- wave0 exports slice: coalesced 8B sc1 stores, then flag ----
    if (tid < 64) {
      const int bl = tid >> 2;             // batch 0..15
      const int c0 = (tid & 3) * 4;        // 4 f16 = 8B
      const u64 v = *(const u64*)(hOut + bl * JW + c0);
      u64* hdst = (u64*)(h_g + ((size_t)((((s + 1) & 1) * 2 + dir) * NGRP + grp) * BG + bl) * HH
                         + slice * JW + c0);
      __hip_atomic_store(hdst, v, __ATOMIC_RELAXED, __HIP_MEMORY_SCOPE_AGENT);
      const int slot = sSlot[bl];
      if (slot >= 0) {
        const u64 hv = sMask[bl] > 0.f ? v : 0ULL;   // ys = h * m
        *(u64*)(hist + ((size_t)(dir * BB + grp * BG + bl) * NSLOT + slot) * HH
                + slice * JW + c0) = hv;
      }
    }

    if (s + 1 < TT) {
      asm volatile("s_waitcnt vmcnt(0)" ::: "memory");   // h stores at L3 before flag
      if (tid == 0)
        __hip_atomic_store(flags + dom * 32 + slice, (unsigned)(s + 1),
                           __ATOMIC_RELAXED, __HIP_MEMORY_SCOPE_AGENT);
      // poll all 32 slice flags of this domain (one 128B line)
      const unsigned tgt = (unsigned)(s + 1);
      const unsigned* fl = flags + dom * 32 + (lane & 31);
      for (;;) {
        const unsigned v = __hip_atomic_load(fl, __ATOMIC_RELAXED, __HIP_MEMORY_SCOPE_AGENT);
        if (__all((lane >= 32) | (v >= tgt))) break;
        __builtin_amdgcn_s_sleep(1);
      }
      __builtin_amdgcn_sched_barrier(0);
      asm volatile("" ::: "memory");       // no h_g load hoisting above the poll
    }
  }
}

// ---------------- gather boundary outputs ----------------
__global__ __launch_bounds__(256) void gather_out(
    const int* __restrict__ bnd, const int* __restrict__ slotmap,
    const f16* __restrict__ hist, float* __restrict__ out)
{
  const int bw = blockIdx.x;
  const int b = bw >> 6;
  const int w = bw & 63;
  const int k = threadIdx.x * 8;
  const int iv = bnd[b * 65 + w];
  const int jv = bnd[b * 65 + w + 1];
  const bool valid = (iv != -1) && (jv != -1);
  float* dst = out + (size_t)bw * 2048 + k;
  if (valid) {
    const int seg = k >> 9;                    // 0:h_f(i) 1:h_b(i) 2:h_f(j) 3:h_b(j)
    int ts = (seg < 2) ? iv : jv;
    ts = ts < 0 ? 0 : (ts > TT - 1 ? TT - 1 : ts);
    const int dirn = seg & 1;
    const int slot = slotmap[b * TT + ts];
    const f16* src = hist + ((size_t)(dirn * BB + b) * NSLOT + slot) * HH + (k & 511);
    f16x8 v = *(const f16x8*)src;
    float4 o0 = make_float4((float)v[0], (float)v[1], (float)v[2], (float)v[3]);
    float4 o1 = make_float4((float)v[4], (float)v[5], (float)v[6], (float)v[7]);
    *(float4*)dst = o0;
    *(float4*)(dst + 4) = o1;
  } else {
    float4 z = make_float4(0.f, 0.f, 0.f, 0.f);
    *(float4*)dst = z;
    *(float4*)(dst + 4) = z;
  }
}

extern "C" void kernel_launch(void* const* d_in, const int* in_sizes, int n_in,
                              void* d_out, int out_size, void* d_ws, size_t ws_size,
                              hipStream_t stream)
{
  (void)in_sizes; (void)n_in; (void)out_size; (void)ws_size;
  const int* ids     = (const int*)d_in[0];
  const int* maskI   = (const int*)d_in[1];
  const int* bnd     = (const int*)d_in[2];
  const float* emb   = (const float*)d_in[3];
  const float* Wih_f = (const float*)d_in[4];
  const float* Whh_f = (const float*)d_in[5];
  const float* b_f   = (const float*)d_in[6];
  const float* Wih_b = (const float*)d_in[7];
  const float* Whh_b = (const float*)d_in[8];
  const float* b_b   = (const float*)d_in[9];

  char* ws = (char*)d_ws;
  unsigned* flags = (unsigned*)ws;                                 // 4 KiB (8 lines)
  int* slotmap  = (int*)(ws + 4096);                               // 128 KiB
  f16* h_g      = (f16*)(ws + 4096 + 131072);                      // 256 KiB
  f16* hist     = (f16*)(ws + 4096 + 131072 + 262144);             // ~16.5 MiB

  hipMemsetAsync(flags, 0, 4096, stream);
  build_map<<<dim3(BB), dim3(64), 0, stream>>>(bnd, slotmap);
  lstm_scan<<<dim3(256), dim3(256), 0, stream>>>(ids, maskI, emb,
      Wih_f, Whh_f, b_f, Whh_b == nullptr ? b_b : Wih_b, Whh_b, b_b, slotmap, h_g, hist, flags);
  gather_out<<<dim3(BB * 64), dim3(256), 0, stream>>>(bnd, slotmap, hist, (float*)d_out);
}